// Round 17
// baseline (104.033 us; speedup 1.0000x reference)
//
#include <hip/hip_runtime.h>
#include <hip/hip_bf16.h>
#include <math.h>

#define H 8
#define K 4
#define NN 4
#define D 256
#define NQ 1024
#define NKV 2048
#define BATCH 2
#define CH 32           // D / H
#define GC 16           // grid cells per axis
#define CELLH 0.0625f   // 1/16

// workspace layout (bytes) — vws bf16 (2 MB used of the 4 MB slot)
#define OFF_LOC   0u          // 65536 * float2 = 512 KB
#define OFF_ATTN  524288u     // 65536 * f32    = 256 KB
#define OFF_VWS   786432u     // 16*2048*32 bf16 = 2 MB (slot sized 4 MB)
#define OFF_HEAD  4980736u    // 2*1024*256 f32 = 2 MB
#define OFF_PTS   7077888u    // 2*2048 float4  = 64 KB (cell-sorted)
#define OFF_CST   7143424u    // 2*257 i32 cell starts (+pad)
#define WS_NEED   7147520u

typedef unsigned short ushortb;

__device__ __forceinline__ float bf2f(ushortb u) {
    return __uint_as_float((unsigned)u << 16);
}
__device__ __forceinline__ ushortb f2bf(float f) {
    __hip_bfloat16 h = __float2bfloat16(f);       // RNE
    return *(ushortb*)&h;
}

// ---------------------------------------------------------------------------
// Branchless lexicographic (d, idx) stable top-4 insert — f32/i32 only.
// Order-independent; reproduces lax.top_k (d asc, ties idx asc).
// ---------------------------------------------------------------------------
__device__ __forceinline__ void lexins(float t, int n,
                                       float& d0, float& d1, float& d2, float& d3,
                                       int& i0, int& i1, int& i2, int& i3) {
    bool c0 = (t < d0) || (t == d0 && n < i0);
    bool c1 = (t < d1) || (t == d1 && n < i1);
    bool c2 = (t < d2) || (t == d2 && n < i2);
    bool c3 = (t < d3) || (t == d3 && n < i3);
    d3 = c3 ? (c2 ? d2 : t) : d3;   i3 = c3 ? (c2 ? i2 : n) : i3;
    d2 = c2 ? (c1 ? d1 : t) : d2;   i2 = c2 ? (c1 ? i1 : n) : i2;
    d1 = c1 ? (c0 ? d0 : t) : d1;   i1 = c1 ? (c0 ? i0 : n) : i1;
    d0 = c0 ? t : d0;               i0 = c0 ? n : i0;
}

// DEDUP variant: for ring re-merges where lists share phase-1 survivors.
__device__ __forceinline__ void lexins_d(float t, int n,
                                         float& d0, float& d1, float& d2, float& d3,
                                         int& i0, int& i1, int& i2, int& i3) {
    bool nd = !((n == i0) | (n == i1) | (n == i2) | (n == i3));
    bool c0 = nd && ((t < d0) || (t == d0 && n < i0));
    bool c1 = nd && ((t < d1) || (t == d1 && n < i1));
    bool c2 = nd && ((t < d2) || (t == d2 && n < i2));
    bool c3 = nd && ((t < d3) || (t == d3 && n < i3));
    d3 = c3 ? (c2 ? d2 : t) : d3;   i3 = c3 ? (c2 ? i2 : n) : i3;
    d2 = c2 ? (c1 ? d1 : t) : d2;   i2 = c2 ? (c1 ? i1 : n) : i2;
    d1 = c1 ? (c0 ? d0 : t) : d1;   i1 = c1 ? (c0 ? i0 : n) : i1;
    d0 = c0 ? t : d0;               i0 = c0 ? n : i0;
}

// strict-< variant for the ascending-order brute-force fallback
__device__ __forceinline__ void bins4(float t, int n,
                                      float& d0, float& d1, float& d2, float& d3,
                                      int& i0, int& i1, int& i2, int& i3) {
    bool c0 = t < d0, c1 = t < d1, c2 = t < d2, c3 = t < d3;
    d3 = c3 ? (c2 ? d2 : t) : d3;   i3 = c3 ? (c2 ? i2 : n) : i3;
    d2 = c2 ? (c1 ? d1 : t) : d2;   i2 = c2 ? (c1 ? i1 : n) : i2;
    d1 = c1 ? (c0 ? d0 : t) : d1;   i1 = c1 ? (c0 ? i0 : n) : i1;
    d0 = c0 ? t : d0;               i0 = c0 ? n : i0;
}

// ---------------------------------------------------------------------------
// Kernel FRONT (fused, 256 threads): offattn (2 rows/block) | values | bin
// (validated in round 16)
// ---------------------------------------------------------------------------
__global__ void k_front(const float* __restrict__ q, const float* __restrict__ qpos,
                        const float* __restrict__ Woff, const float* __restrict__ boff,
                        const float* __restrict__ Wattn, const float* __restrict__ battn,
                        const float* __restrict__ kv, const float* __restrict__ Wv,
                        const float* __restrict__ bv, const float* __restrict__ kvpos,
                        float* __restrict__ loc, float* __restrict__ attnw,
                        ushortb* __restrict__ vwsb,
                        float4* __restrict__ pts4, int* __restrict__ cellStart) {
    #pragma clang fp contract(off)
    if (blockIdx.x < (BATCH * NQ) / 2) {
        int r0 = blockIdx.x * 2;
        __shared__ float qs2[2][D];
        for (int t = threadIdx.x; t < 2 * D; t += 256) qs2[t >> 8][t & 255] = q[(size_t)r0 * D + t];
        __syncthreads();
        int half = threadIdx.x >> 7;             // 0 or 1
        int j = threadIdx.x & 127;
        int row = r0 + half;
        int b = row >> 10, qi = row & (NQ - 1);
        const float* qs = qs2[half];
        if (j < 64) {
            float acc = 0.0f;
            for (int d = 0; d < D; ++d) acc = fmaf(qs[d], Woff[d * 64 + j], acc);
            float off = acc + boff[j];           // bias after, like np
            int xy = j & 1;
            int hk = j >> 1;                     // h*4 + k
            int h = hk >> 2, k = hk & 3;
            float L = qpos[(size_t)row * 2 + xy] + off;
            int g = ((b * H + h) * NQ + qi) * K + k;
            loc[(size_t)g * 2 + xy] = L;
        } else if (j < 96) {
            int j2 = j - 64;                     // h*4 + k
            float acc = 0.0f;
            for (int d = 0; d < D; ++d) acc = fmaf(qs[d], Wattn[d * 32 + j2], acc);
            acc += battn[j2];
            float m = acc;
            m = fmaxf(m, __shfl_xor(m, 1));
            m = fmaxf(m, __shfl_xor(m, 2));
            float e = expf(acc - m);
            float s = e;
            s += __shfl_xor(s, 1);
            s += __shfl_xor(s, 2);
            float w = e / s;
            int h = j2 >> 2, k = j2 & 3;
            attnw[((b * H + h) * NQ + qi) * K + k] = w;
        }
        return;
    }
    if (blockIdx.x < (BATCH * NQ) / 2 + BATCH * NKV / 4) {
        int r0 = (blockIdx.x - (BATCH * NQ) / 2) * 4;
        __shared__ float ks[4][D];
        for (int t = threadIdx.x; t < 4 * D; t += 256) ks[t >> 8][t & 255] = kv[(size_t)r0 * D + t];
        __syncthreads();
        int c = threadIdx.x;                     // h*32 + cc
        float a0 = 0.f, a1 = 0.f, a2 = 0.f, a3 = 0.f;
        for (int d = 0; d < D; ++d) {
            float w = Wv[d * D + c];
            a0 = fmaf(ks[0][d], w, a0); a1 = fmaf(ks[1][d], w, a1);
            a2 = fmaf(ks[2][d], w, a2); a3 = fmaf(ks[3][d], w, a3);
        }
        float bias = bv[c];
        a0 += bias; a1 += bias; a2 += bias; a3 += bias;
        int h = c >> 5, cc = c & 31;
        float va[4] = {a0, a1, a2, a3};
        for (int r = 0; r < 4; ++r) {
            int row = r0 + r;
            int b = row >> 11, n = row & (NKV - 1);
            vwsb[(((size_t)(b * H + h) * NKV) + n) * CH + cc] = f2bf(va[r]);
        }
        return;
    }
    {
        int b = blockIdx.x - ((BATCH * NQ) / 2 + BATCH * NKV / 4);
        int tid = threadIdx.x;
        __shared__ int cnt[GC * GC];
        __shared__ int ofs[GC * GC + 1];
        __shared__ int cur[GC * GC];
        if (tid < GC * GC) cnt[tid] = 0;
        __syncthreads();
        for (int n = tid; n < NKV; n += 256) {
            float x = kvpos[(size_t)(b * NKV + n) * 2 + 0];
            float y = kvpos[(size_t)(b * NKV + n) * 2 + 1];
            int ix = min(GC - 1, max(0, (int)floorf(x * (float)GC)));
            int iy = min(GC - 1, max(0, (int)floorf(y * (float)GC)));
            atomicAdd(&cnt[iy * GC + ix], 1);
        }
        __syncthreads();
        if (tid == 0) {
            int s = 0;
            for (int c = 0; c < GC * GC; ++c) { ofs[c] = s; s += cnt[c]; }
            ofs[GC * GC] = s;
        }
        __syncthreads();
        for (int t = tid; t < GC * GC + 1; t += 256) cellStart[b * 257 + t] = ofs[t];
        if (tid < GC * GC) cur[tid] = ofs[tid];
        __syncthreads();
        for (int n = tid; n < NKV; n += 256) {
            float x = kvpos[(size_t)(b * NKV + n) * 2 + 0];
            float y = kvpos[(size_t)(b * NKV + n) * 2 + 1];
            int ix = min(GC - 1, max(0, (int)floorf(x * (float)GC)));
            int iy = min(GC - 1, max(0, (int)floorf(y * (float)GC)));
            int pos = atomicAdd(&cur[iy * GC + ix], 1);
            pts4[(size_t)b * NKV + pos] = make_float4(-2.0f * x, -2.0f * y, x * x + y * y, (float)n);
        }
    }
}

// ---------------------------------------------------------------------------
// Kernel 3: grid 4-NN (R9 structure) with 2-DEEP SOFTWARE PIPELINE in the
// phase-1 scan: next iteration's 4 loads are issued before this iteration's
// inserts (addresses depend only on f -> insert order per lane unchanged ->
// numerics bitwise-identical).  Ring/merges/tail unchanged.
// ---------------------------------------------------------------------------
__global__ void k_knn_grid2(const float* __restrict__ kvpos, const float* __restrict__ loc,
                            const float* __restrict__ attnw, const ushortb* __restrict__ vwsb,
                            const float* __restrict__ sp,
                            const float4* __restrict__ pts4, const int* __restrict__ cellStart,
                            float* __restrict__ head) {
    #pragma clang fp contract(off)
    int lane = threadIdx.x;
    int s = lane & 7;
    int g = blockIdx.x * 32 + (lane >> 3);    // point id
    int b = g >> 15;
    int bh = g >> 12;

    __shared__ int cst[GC * GC + 1];
    for (int i = threadIdx.x; i < GC * GC + 1; i += 256) cst[i] = cellStart[b * 257 + i];
    __syncthreads();

    const float4* gp = pts4 + (size_t)b * NKV;
    float2 L = ((const float2*)loc)[g];
    float lx = L.x, ly = L.y;
    float sl = lx * lx + ly * ly;

    int ix = min(GC - 1, max(0, (int)floorf(lx * (float)GC)));
    int iy = min(GC - 1, max(0, (int)floorf(ly * (float)GC)));

    float d0 = 1e30f, d1 = 1e30f, d2 = 1e30f, d3 = 1e30f;
    int i0 = 0x7FFFFFFF, i1 = 0x7FFFFFFF, i2 = 0x7FFFFFFF, i3 = 0x7FFFFFFF;

#define INS1(P) { float tt = (sl + (P).z) + fmaf(ly, (P).y, lx * (P).x);      \
                  lexins(tt, (int)(P).w, d0, d1, d2, d3, i0, i1, i2, i3); }

    // ---- phase 1: clamped 3x3 box, flattened rows, 4-wide batched loads,
    //      2-deep pipelined (load f+32 before inserting f) ----
    {
        int bx0 = max(ix - 1, 0), bx1 = min(ix + 1, GC - 1);
        int by0 = max(iy - 1, 0), by1 = min(iy + 1, GC - 1);
        int a0 = cst[by0 * GC + bx0];
        int l0 = cst[by0 * GC + bx1 + 1] - a0;
        int a1 = 0, l1 = 0, a2 = 0, l2 = 0;
        if (by0 + 1 <= by1) { a1 = cst[(by0 + 1) * GC + bx0]; l1 = cst[(by0 + 1) * GC + bx1 + 1] - a1; }
        if (by0 + 2 <= by1) { a2 = cst[(by0 + 2) * GC + bx0]; l2 = cst[(by0 + 2) * GC + bx1 + 1] - a2; }
        int l01 = l0 + l1;
        int m = l01 + l2;

#define F2J(F) ((F) < l0 ? a0 + (F) : ((F) < l01 ? a1 + ((F) - l0) : a2 + ((F) - l01)))

        int f = s;
        if (f + 24 < m) {
            // prologue: load batch for f
            float4 p0 = gp[F2J(f)], p1 = gp[F2J(f + 8)], p2 = gp[F2J(f + 16)], p3 = gp[F2J(f + 24)];
            for (; f + 56 < m; f += 32) {
                int fn = f + 32;
                float4 q0 = gp[F2J(fn)], q1 = gp[F2J(fn + 8)];
                float4 q2 = gp[F2J(fn + 16)], q3 = gp[F2J(fn + 24)];
                INS1(p0); INS1(p1); INS1(p2); INS1(p3);
                p0 = q0; p1 = q1; p2 = q2; p3 = q3;
            }
            INS1(p0); INS1(p1); INS1(p2); INS1(p3);
            f += 32;
        }
        if (f < m) {
            // remainder: 1-deep lookahead
            float4 p = gp[F2J(f)];
            for (; f + 8 < m; f += 8) {
                float4 q = gp[F2J(f + 8)];
                INS1(p);
                p = q;
            }
            INS1(p);
        }
#undef F2J
    }

#define MERGE_P(M) {                                                           \
        float e0 = __shfl_xor(d0, M), e1 = __shfl_xor(d1, M);                  \
        float e2 = __shfl_xor(d2, M), e3 = __shfl_xor(d3, M);                  \
        int j0 = __shfl_xor(i0, M), j1 = __shfl_xor(i1, M);                    \
        int j2 = __shfl_xor(i2, M), j3 = __shfl_xor(i3, M);                    \
        lexins(e0, j0, d0, d1, d2, d3, i0, i1, i2, i3);                        \
        lexins(e1, j1, d0, d1, d2, d3, i0, i1, i2, i3);                        \
        lexins(e2, j2, d0, d1, d2, d3, i0, i1, i2, i3);                        \
        lexins(e3, j3, d0, d1, d2, d3, i0, i1, i2, i3);                        \
    }
#define MERGE_D(M) {                                                           \
        float e0 = __shfl_xor(d0, M), e1 = __shfl_xor(d1, M);                  \
        float e2 = __shfl_xor(d2, M), e3 = __shfl_xor(d3, M);                  \
        int j0 = __shfl_xor(i0, M), j1 = __shfl_xor(i1, M);                    \
        int j2 = __shfl_xor(i2, M), j3 = __shfl_xor(i3, M);                    \
        lexins_d(e0, j0, d0, d1, d2, d3, i0, i1, i2, i3);                      \
        lexins_d(e1, j1, d0, d1, d2, d3, i0, i1, i2, i3);                      \
        lexins_d(e2, j2, d0, d1, d2, d3, i0, i1, i2, i3);                      \
        lexins_d(e3, j3, d0, d1, d2, d3, i0, i1, i2, i3);                      \
    }

    MERGE_P(1);
    MERGE_P(2);
    MERGE_P(4);

    auto done_at = [&](int r) -> bool {
        int bx0 = ix - r, bx1 = ix + r, by0 = iy - r, by1 = iy + r;
        float bound = 1e30f;
        if (bx0 > 0)      bound = fminf(bound, lx - (float)bx0 * CELLH);
        if (bx1 < GC - 1) bound = fminf(bound, (float)(bx1 + 1) * CELLH - lx);
        if (by0 > 0)      bound = fminf(bound, ly - (float)by0 * CELLH);
        if (by1 < GC - 1) bound = fminf(bound, (float)(by1 + 1) * CELLH - ly);
        bool covered = (bx0 <= 0 && bx1 >= GC - 1 && by0 <= 0 && by1 >= GC - 1);
        return covered || (d3 < bound * bound - 1e-5f);
    };

#define SCAN_RANGE_S(JLO, JHI)                                       \
    for (int j = (JLO) + s; j < (JHI); j += 8) {                     \
        float4 p = gp[j];                                            \
        INS1(p);                                                     \
    }

    int r = 1;
    bool need = !done_at(1);
    while (__any(need)) {
        ++r;
        if (need) {
            int ry0 = iy - r, ry1 = iy + r;
            int rx0 = ix - r, rx1 = ix + r;
            int ca = max(rx0, 0), cb = min(rx1, GC - 1);
            if (ry0 >= 0)      { int base = ry0 * GC; SCAN_RANGE_S(cst[base + ca], cst[base + cb + 1]); }
            if (ry1 <= GC - 1) { int base = ry1 * GC; SCAN_RANGE_S(cst[base + ca], cst[base + cb + 1]); }
            int ya = max(ry0 + 1, 0), yb = min(ry1 - 1, GC - 1);
            if (rx0 >= 0)      for (int cy = ya; cy <= yb; ++cy) { int c = cy * GC + rx0; SCAN_RANGE_S(cst[c], cst[c + 1]); }
            if (rx1 <= GC - 1) for (int cy = ya; cy <= yb; ++cy) { int c = cy * GC + rx1; SCAN_RANGE_S(cst[c], cst[c + 1]); }
            MERGE_D(1);
            MERGE_D(2);
            MERGE_D(4);
            need = !done_at(r);
        }
    }
#undef SCAN_RANGE_S
#undef MERGE_P
#undef MERGE_D
#undef INS1

    // ---- tail, split 8-way over channel chunks (t = s), bf16 gather ----
    int bb = bh >> 3, h = bh & 7;
    int qi = (g >> 2) & (NQ - 1);
    float power = fmaxf(sp[0], 0.0f) + 1e-6f;
    int idx[4] = {i0, i1, i2, i3};
    float z[4];
    #pragma unroll
    for (int u = 0; u < 4; ++u) {
        float kx = kvpos[(size_t)(bb * NKV + idx[u]) * 2 + 0];
        float ky = kvpos[(size_t)(bb * NKV + idx[u]) * 2 + 1];
        float dx = kx - lx;
        float dy = ky - ly;
        float dist = sqrtf(dx * dx + dy * dy) + 1e-6f;
        z[u] = -power * dist;
    }
    float m = fmaxf(fmaxf(z[0], z[1]), fmaxf(z[2], z[3]));
    float e0 = expf(z[0] - m), e1 = expf(z[1] - m), e2 = expf(z[2] - m), e3 = expf(z[3] - m);
    float esum = e0 + e1 + e2 + e3;
    float w0 = e0 / esum, w1 = e1 / esum, w2 = e2 / esum, w3 = e3 / esum;

    const ushort4* vp0 = (const ushort4*)(vwsb + ((size_t)bh * NKV + i0) * CH);
    const ushort4* vp1 = (const ushort4*)(vwsb + ((size_t)bh * NKV + i1) * CH);
    const ushort4* vp2 = (const ushort4*)(vwsb + ((size_t)bh * NKV + i2) * CH);
    const ushort4* vp3 = (const ushort4*)(vwsb + ((size_t)bh * NKV + i3) * CH);
    float a = attnw[g];
    float4* hp = (float4*)(head + ((size_t)(bb * NQ + qi)) * D + h * CH);
    {
        ushort4 u0 = vp0[s], u1 = vp1[s], u2 = vp2[s], u3 = vp3[s];
        float4 rr;
        rr.x = a * (w0 * bf2f(u0.x) + w1 * bf2f(u1.x) + w2 * bf2f(u2.x) + w3 * bf2f(u3.x));
        rr.y = a * (w0 * bf2f(u0.y) + w1 * bf2f(u1.y) + w2 * bf2f(u2.y) + w3 * bf2f(u3.y));
        rr.z = a * (w0 * bf2f(u0.z) + w1 * bf2f(u1.z) + w2 * bf2f(u2.z) + w3 * bf2f(u3.z));
        rr.w = a * (w0 * bf2f(u0.w) + w1 * bf2f(u1.w) + w2 * bf2f(u2.w) + w3 * bf2f(u3.w));
        rr.x += __shfl_xor(rr.x, 8); rr.x += __shfl_xor(rr.x, 16);  // sum over k
        rr.y += __shfl_xor(rr.y, 8); rr.y += __shfl_xor(rr.y, 16);
        rr.z += __shfl_xor(rr.z, 8); rr.z += __shfl_xor(rr.z, 16);
        rr.w += __shfl_xor(rr.w, 8); rr.w += __shfl_xor(rr.w, 16);
        if (((lane >> 3) & 3) == 0) hp[s] = rr;                     // k==0 lanes write
    }
}

// Fallback (ws too small): brute-force fused scan (round-4 validated path,
// bf16 value gather).  Requires loc/attnw/vwsb already computed by k_front.
__global__ void k_knn_fused(const float* __restrict__ kvpos, const float* __restrict__ loc,
                            const float* __restrict__ attnw, const ushortb* __restrict__ vwsb,
                            const float* __restrict__ sp, float* __restrict__ head) {
    #pragma clang fp contract(off)
    int g = blockIdx.x * 256 + threadIdx.x;
    int bh = g >> 12;
    int b = bh >> 3;
    __shared__ float sx[NKV];
    __shared__ float sy[NKV];
    __shared__ float sz[NKV];
    for (int n = threadIdx.x; n < NKV; n += 256) {
        float x = kvpos[(size_t)(b * NKV + n) * 2 + 0];
        float y = kvpos[(size_t)(b * NKV + n) * 2 + 1];
        sx[n] = -2.0f * x;
        sy[n] = -2.0f * y;
        sz[n] = x * x + y * y;
    }
    __syncthreads();
    float2 L = ((const float2*)loc)[g];
    float lx = L.x, ly = L.y;
    float sl = lx * lx + ly * ly;
    const float4* x4 = (const float4*)sx;
    const float4* y4 = (const float4*)sy;
    const float4* z4 = (const float4*)sz;
    float d0 = 1e30f, d1 = 1e30f, d2 = 1e30f, d3 = 1e30f;
    int i0 = 0, i1 = 0, i2 = 0, i3 = 0;
    for (int n = 0; n < NKV; n += 4) {
        int v = n >> 2;
        float4 xA = x4[v], yA = y4[v], zA = z4[v];
        float t0 = (sl + zA.x) + fmaf(ly, yA.x, lx * xA.x);
        float t1 = (sl + zA.y) + fmaf(ly, yA.y, lx * xA.y);
        float t2 = (sl + zA.z) + fmaf(ly, yA.z, lx * xA.z);
        float t3 = (sl + zA.w) + fmaf(ly, yA.w, lx * xA.w);
        bins4(t0, n + 0, d0, d1, d2, d3, i0, i1, i2, i3);
        bins4(t1, n + 1, d0, d1, d2, d3, i0, i1, i2, i3);
        bins4(t2, n + 2, d0, d1, d2, d3, i0, i1, i2, i3);
        bins4(t3, n + 3, d0, d1, d2, d3, i0, i1, i2, i3);
    }
    float power = fmaxf(sp[0], 0.0f) + 1e-6f;
    int h = bh & 7;
    int qi = (g >> 2) & (NQ - 1);
    int k = g & 3;
    int idx[4] = {i0, i1, i2, i3};
    float z[4];
    #pragma unroll
    for (int u = 0; u < 4; ++u) {
        float kx = kvpos[(size_t)(b * NKV + idx[u]) * 2 + 0];
        float ky = kvpos[(size_t)(b * NKV + idx[u]) * 2 + 1];
        float dx = kx - lx;
        float dy = ky - ly;
        float dist = sqrtf(dx * dx + dy * dy) + 1e-6f;
        z[u] = -power * dist;
    }
    float m = fmaxf(fmaxf(z[0], z[1]), fmaxf(z[2], z[3]));
    float e0 = expf(z[0] - m), e1 = expf(z[1] - m), e2 = expf(z[2] - m), e3 = expf(z[3] - m);
    float esum = e0 + e1 + e2 + e3;
    float w0 = e0 / esum, w1 = e1 / esum, w2 = e2 / esum, w3 = e3 / esum;
    const ushort4* vp0 = (const ushort4*)(vwsb + ((size_t)bh * NKV + i0) * CH);
    const ushort4* vp1 = (const ushort4*)(vwsb + ((size_t)bh * NKV + i1) * CH);
    const ushort4* vp2 = (const ushort4*)(vwsb + ((size_t)bh * NKV + i2) * CH);
    const ushort4* vp3 = (const ushort4*)(vwsb + ((size_t)bh * NKV + i3) * CH);
    float a = attnw[g];
    float4 acc[8];
    #pragma unroll
    for (int t = 0; t < 8; ++t) {
        ushort4 u0 = vp0[t], u1 = vp1[t], u2 = vp2[t], u3 = vp3[t];
        float4 r;
        r.x = a * (w0 * bf2f(u0.x) + w1 * bf2f(u1.x) + w2 * bf2f(u2.x) + w3 * bf2f(u3.x));
        r.y = a * (w0 * bf2f(u0.y) + w1 * bf2f(u1.y) + w2 * bf2f(u2.y) + w3 * bf2f(u3.y));
        r.z = a * (w0 * bf2f(u0.z) + w1 * bf2f(u1.z) + w2 * bf2f(u2.z) + w3 * bf2f(u3.z));
        r.w = a * (w0 * bf2f(u0.w) + w1 * bf2f(u1.w) + w2 * bf2f(u2.w) + w3 * bf2f(u3.w));
        r.x += __shfl_xor(r.x, 1); r.x += __shfl_xor(r.x, 2);
        r.y += __shfl_xor(r.y, 1); r.y += __shfl_xor(r.y, 2);
        r.z += __shfl_xor(r.z, 1); r.z += __shfl_xor(r.z, 2);
        r.w += __shfl_xor(r.w, 1); r.w += __shfl_xor(r.w, 2);
        acc[t] = r;
    }
    float4* hp = (float4*)(head + ((size_t)(b * NQ + qi)) * D + h * CH);
    hp[k * 2]     = acc[k * 2];
    hp[k * 2 + 1] = acc[k * 2 + 1];
}

// ---------------------------------------------------------------------------
// Kernel 4: out = head @ W_out + b_out  (f32 store; R9 version, 4 rows/block)
// ---------------------------------------------------------------------------
__global__ void k_out(const float* __restrict__ head, const float* __restrict__ Wout,
                      const float* __restrict__ bout, float* __restrict__ out) {
    int r0 = blockIdx.x * 4;
    __shared__ float hs[4][D];
    for (int t = threadIdx.x; t < 4 * D; t += 256) hs[t >> 8][t & 255] = head[(size_t)r0 * D + t];
    __syncthreads();
    int c = threadIdx.x;
    float a0 = 0.f, a1 = 0.f, a2 = 0.f, a3 = 0.f;
    for (int d = 0; d < D; ++d) {
        float w = Wout[d * D + c];
        a0 = fmaf(hs[0][d], w, a0); a1 = fmaf(hs[1][d], w, a1);
        a2 = fmaf(hs[2][d], w, a2); a3 = fmaf(hs[3][d], w, a3);
    }
    float bias = bout[c];
    out[(size_t)(r0 + 0) * D + c] = a0 + bias;
    out[(size_t)(r0 + 1) * D + c] = a1 + bias;
    out[(size_t)(r0 + 2) * D + c] = a2 + bias;
    out[(size_t)(r0 + 3) * D + c] = a3 + bias;
}

// ---------------------------------------------------------------------------
extern "C" void kernel_launch(void* const* d_in, const int* in_sizes, int n_in,
                              void* d_out, int out_size, void* d_ws, size_t ws_size,
                              hipStream_t stream) {
    (void)in_sizes; (void)n_in; (void)out_size;
    const float* q     = (const float*)d_in[0];
    const float* qpos  = (const float*)d_in[1];
    const float* kv    = (const float*)d_in[2];
    const float* kvp   = (const float*)d_in[3];
    const float* Woff  = (const float*)d_in[4];
    const float* boff  = (const float*)d_in[5];
    const float* Wattn = (const float*)d_in[6];
    const float* battn = (const float*)d_in[7];
    const float* Wv    = (const float*)d_in[8];
    const float* bv    = (const float*)d_in[9];
    const float* Wout  = (const float*)d_in[10];
    const float* bout  = (const float*)d_in[11];
    const float* sp    = (const float*)d_in[12];
    float* out = (float*)d_out;

    char* ws = (char*)d_ws;
    float* loc      = (float*)(ws + OFF_LOC);
    float* attnw    = (float*)(ws + OFF_ATTN);
    ushortb* vwsb   = (ushortb*)(ws + OFF_VWS);
    float* head     = (float*)(ws + OFF_HEAD);
    float4* pts4    = (float4*)(ws + OFF_PTS);
    int* cellStart  = (int*)(ws + OFF_CST);

    bool grid_ok = ws_size >= (size_t)WS_NEED;
    int nfront = (BATCH * NQ) / 2 + BATCH * NKV / 4 + (grid_ok ? BATCH : 0);
    hipLaunchKernelGGL(k_front, dim3(nfront), dim3(256), 0, stream,
                       q, qpos, Woff, boff, Wattn, battn, kv, Wv, bv, kvp,
                       loc, attnw, vwsb, pts4, cellStart);
    if (grid_ok) {
        hipLaunchKernelGGL(k_knn_grid2, dim3(BATCH * H * NQ * K / 32), dim3(256), 0, stream,
                           kvp, loc, attnw, vwsb, sp, pts4, cellStart, head);
    } else {
        hipLaunchKernelGGL(k_knn_fused, dim3(BATCH * H * NQ * K / 256), dim3(256), 0, stream,
                           kvp, loc, attnw, vwsb, sp, head);
    }
    hipLaunchKernelGGL(k_out, dim3(BATCH * NQ / 4), dim3(256), 0, stream,
                       head, Wout, bout, out);
}

// Round 18
// 103.652 us; speedup vs baseline: 1.0037x; 1.0037x over previous
//
#include <hip/hip_runtime.h>
#include <hip/hip_bf16.h>
#include <math.h>

#define H 8
#define K 4
#define NN 4
#define D 256
#define NQ 1024
#define NKV 2048
#define BATCH 2
#define CH 32           // D / H
#define GC 16           // grid cells per axis
#define CELLH 0.0625f   // 1/16

// workspace layout (bytes) — vws bf16 (2 MB used of the 4 MB slot)
#define OFF_LOC   0u          // 65536 * float2 = 512 KB
#define OFF_ATTN  524288u     // 65536 * f32    = 256 KB
#define OFF_VWS   786432u     // 16*2048*32 bf16 = 2 MB (slot sized 4 MB)
#define OFF_HEAD  4980736u    // 2*1024*256 f32 = 2 MB
#define OFF_PTS   7077888u    // 2*2048 float4  = 64 KB (cell-sorted)
#define OFF_CST   7143424u    // 2*257 i32 cell starts (+pad)
#define WS_NEED   7147520u

typedef unsigned short ushortb;

__device__ __forceinline__ float bf2f(ushortb u) {
    return __uint_as_float((unsigned)u << 16);
}
__device__ __forceinline__ ushortb f2bf(float f) {
    __hip_bfloat16 h = __float2bfloat16(f);       // RNE
    return *(ushortb*)&h;
}

// ---------------------------------------------------------------------------
// Branchless lexicographic (d, idx) stable top-4 insert — f32/i32 only.
// Order-independent; reproduces lax.top_k (d asc, ties idx asc).
// ---------------------------------------------------------------------------
__device__ __forceinline__ void lexins(float t, int n,
                                       float& d0, float& d1, float& d2, float& d3,
                                       int& i0, int& i1, int& i2, int& i3) {
    bool c0 = (t < d0) || (t == d0 && n < i0);
    bool c1 = (t < d1) || (t == d1 && n < i1);
    bool c2 = (t < d2) || (t == d2 && n < i2);
    bool c3 = (t < d3) || (t == d3 && n < i3);
    d3 = c3 ? (c2 ? d2 : t) : d3;   i3 = c3 ? (c2 ? i2 : n) : i3;
    d2 = c2 ? (c1 ? d1 : t) : d2;   i2 = c2 ? (c1 ? i1 : n) : i2;
    d1 = c1 ? (c0 ? d0 : t) : d1;   i1 = c1 ? (c0 ? i0 : n) : i1;
    d0 = c0 ? t : d0;               i0 = c0 ? n : i0;
}

// DEDUP variant: for ring re-merges where lists share phase-1 survivors.
__device__ __forceinline__ void lexins_d(float t, int n,
                                         float& d0, float& d1, float& d2, float& d3,
                                         int& i0, int& i1, int& i2, int& i3) {
    bool nd = !((n == i0) | (n == i1) | (n == i2) | (n == i3));
    bool c0 = nd && ((t < d0) || (t == d0 && n < i0));
    bool c1 = nd && ((t < d1) || (t == d1 && n < i1));
    bool c2 = nd && ((t < d2) || (t == d2 && n < i2));
    bool c3 = nd && ((t < d3) || (t == d3 && n < i3));
    d3 = c3 ? (c2 ? d2 : t) : d3;   i3 = c3 ? (c2 ? i2 : n) : i3;
    d2 = c2 ? (c1 ? d1 : t) : d2;   i2 = c2 ? (c1 ? i1 : n) : i2;
    d1 = c1 ? (c0 ? d0 : t) : d1;   i1 = c1 ? (c0 ? i0 : n) : i1;
    d0 = c0 ? t : d0;               i0 = c0 ? n : i0;
}

// strict-< variant for the ascending-order brute-force fallback
__device__ __forceinline__ void bins4(float t, int n,
                                      float& d0, float& d1, float& d2, float& d3,
                                      int& i0, int& i1, int& i2, int& i3) {
    bool c0 = t < d0, c1 = t < d1, c2 = t < d2, c3 = t < d3;
    d3 = c3 ? (c2 ? d2 : t) : d3;   i3 = c3 ? (c2 ? i2 : n) : i3;
    d2 = c2 ? (c1 ? d1 : t) : d2;   i2 = c2 ? (c1 ? i1 : n) : i2;
    d1 = c1 ? (c0 ? d0 : t) : d1;   i1 = c1 ? (c0 ? i0 : n) : i1;
    d0 = c0 ? t : d0;               i0 = c0 ? n : i0;
}

// ---------------------------------------------------------------------------
// Kernel FRONT (fused, 256 threads):
//  blocks [0, 1024):       off/attn projections, 2 rows/block (two 128-thread
//                          halves; per-(row,output) fmaf chain bitwise-
//                          identical to the validated 1-row version)
//  blocks [1024, 2048):    values = kv@W_v + b_v -> bf16 [b*H][n_kv][32]
//  blocks [2048, 2048+B):  kv binning into 16x16 cells
// ---------------------------------------------------------------------------
__global__ void k_front(const float* __restrict__ q, const float* __restrict__ qpos,
                        const float* __restrict__ Woff, const float* __restrict__ boff,
                        const float* __restrict__ Wattn, const float* __restrict__ battn,
                        const float* __restrict__ kv, const float* __restrict__ Wv,
                        const float* __restrict__ bv, const float* __restrict__ kvpos,
                        float* __restrict__ loc, float* __restrict__ attnw,
                        ushortb* __restrict__ vwsb,
                        float4* __restrict__ pts4, int* __restrict__ cellStart) {
    #pragma clang fp contract(off)
    if (blockIdx.x < (BATCH * NQ) / 2) {
        // ---- offattn: rows r0, r0+1 ----
        int r0 = blockIdx.x * 2;
        __shared__ float qs2[2][D];
        for (int t = threadIdx.x; t < 2 * D; t += 256) qs2[t >> 8][t & 255] = q[(size_t)r0 * D + t];
        __syncthreads();
        int half = threadIdx.x >> 7;             // 0 or 1
        int j = threadIdx.x & 127;
        int row = r0 + half;
        int b = row >> 10, qi = row & (NQ - 1);
        const float* qs = qs2[half];
        if (j < 64) {
            float acc = 0.0f;
            for (int d = 0; d < D; ++d) acc = fmaf(qs[d], Woff[d * 64 + j], acc);
            float off = acc + boff[j];           // bias after, like np
            int xy = j & 1;
            int hk = j >> 1;                     // h*4 + k
            int h = hk >> 2, k = hk & 3;
            float L = qpos[(size_t)row * 2 + xy] + off;
            int g = ((b * H + h) * NQ + qi) * K + k;
            loc[(size_t)g * 2 + xy] = L;
        } else if (j < 96) {
            int j2 = j - 64;                     // h*4 + k
            float acc = 0.0f;
            for (int d = 0; d < D; ++d) acc = fmaf(qs[d], Wattn[d * 32 + j2], acc);
            acc += battn[j2];
            float m = acc;
            m = fmaxf(m, __shfl_xor(m, 1));
            m = fmaxf(m, __shfl_xor(m, 2));
            float e = expf(acc - m);
            float s = e;
            s += __shfl_xor(s, 1);
            s += __shfl_xor(s, 2);
            float w = e / s;
            int h = j2 >> 2, k = j2 & 3;
            attnw[((b * H + h) * NQ + qi) * K + k] = w;
        }
        return;
    }
    if (blockIdx.x < (BATCH * NQ) / 2 + BATCH * NKV / 4) {
        // ---- values: 4 kv rows/block (R9-validated structure, bf16 store) ----
        int r0 = (blockIdx.x - (BATCH * NQ) / 2) * 4;
        __shared__ float ks[4][D];
        for (int t = threadIdx.x; t < 4 * D; t += 256) ks[t >> 8][t & 255] = kv[(size_t)r0 * D + t];
        __syncthreads();
        int c = threadIdx.x;                     // h*32 + cc
        float a0 = 0.f, a1 = 0.f, a2 = 0.f, a3 = 0.f;
        for (int d = 0; d < D; ++d) {
            float w = Wv[d * D + c];
            a0 = fmaf(ks[0][d], w, a0); a1 = fmaf(ks[1][d], w, a1);
            a2 = fmaf(ks[2][d], w, a2); a3 = fmaf(ks[3][d], w, a3);
        }
        float bias = bv[c];
        a0 += bias; a1 += bias; a2 += bias; a3 += bias;
        int h = c >> 5, cc = c & 31;
        float va[4] = {a0, a1, a2, a3};
        for (int r = 0; r < 4; ++r) {
            int row = r0 + r;
            int b = row >> 11, n = row & (NKV - 1);
            vwsb[(((size_t)(b * H + h) * NKV) + n) * CH + cc] = f2bf(va[r]);
        }
        return;
    }
    // ---- bin: one block per batch ----
    {
        int b = blockIdx.x - ((BATCH * NQ) / 2 + BATCH * NKV / 4);
        int tid = threadIdx.x;
        __shared__ int cnt[GC * GC];
        __shared__ int ofs[GC * GC + 1];
        __shared__ int cur[GC * GC];
        if (tid < GC * GC) cnt[tid] = 0;
        __syncthreads();
        for (int n = tid; n < NKV; n += 256) {
            float x = kvpos[(size_t)(b * NKV + n) * 2 + 0];
            float y = kvpos[(size_t)(b * NKV + n) * 2 + 1];
            int ix = min(GC - 1, max(0, (int)floorf(x * (float)GC)));
            int iy = min(GC - 1, max(0, (int)floorf(y * (float)GC)));
            atomicAdd(&cnt[iy * GC + ix], 1);
        }
        __syncthreads();
        if (tid == 0) {
            int s = 0;
            for (int c = 0; c < GC * GC; ++c) { ofs[c] = s; s += cnt[c]; }
            ofs[GC * GC] = s;
        }
        __syncthreads();
        for (int t = tid; t < GC * GC + 1; t += 256) cellStart[b * 257 + t] = ofs[t];
        if (tid < GC * GC) cur[tid] = ofs[tid];
        __syncthreads();
        for (int n = tid; n < NKV; n += 256) {
            float x = kvpos[(size_t)(b * NKV + n) * 2 + 0];
            float y = kvpos[(size_t)(b * NKV + n) * 2 + 1];
            int ix = min(GC - 1, max(0, (int)floorf(x * (float)GC)));
            int iy = min(GC - 1, max(0, (int)floorf(y * (float)GC)));
            int pos = atomicAdd(&cur[iy * GC + ix], 1);
            pts4[(size_t)b * NKV + pos] = make_float4(-2.0f * x, -2.0f * y, x * x + y * y, (float)n);
        }
    }
}

// ---------------------------------------------------------------------------
// Kernel 3 (R9-validated structure): grid 4-NN, 8 lanes/point, 3x3 box +
// ring, flattened rows + 4-wide batched loads, inline tail (bf16 gather).
// ---------------------------------------------------------------------------
__global__ void k_knn_grid2(const float* __restrict__ kvpos, const float* __restrict__ loc,
                            const float* __restrict__ attnw, const ushortb* __restrict__ vwsb,
                            const float* __restrict__ sp,
                            const float4* __restrict__ pts4, const int* __restrict__ cellStart,
                            float* __restrict__ head) {
    #pragma clang fp contract(off)
    int lane = threadIdx.x;
    int s = lane & 7;
    int g = blockIdx.x * 32 + (lane >> 3);    // point id
    int b = g >> 15;
    int bh = g >> 12;

    __shared__ int cst[GC * GC + 1];
    for (int i = threadIdx.x; i < GC * GC + 1; i += 256) cst[i] = cellStart[b * 257 + i];
    __syncthreads();

    const float4* gp = pts4 + (size_t)b * NKV;
    float2 L = ((const float2*)loc)[g];
    float lx = L.x, ly = L.y;
    float sl = lx * lx + ly * ly;

    int ix = min(GC - 1, max(0, (int)floorf(lx * (float)GC)));
    int iy = min(GC - 1, max(0, (int)floorf(ly * (float)GC)));

    float d0 = 1e30f, d1 = 1e30f, d2 = 1e30f, d3 = 1e30f;
    int i0 = 0x7FFFFFFF, i1 = 0x7FFFFFFF, i2 = 0x7FFFFFFF, i3 = 0x7FFFFFFF;

#define INS1(P) { float tt = (sl + (P).z) + fmaf(ly, (P).y, lx * (P).x);      \
                  lexins(tt, (int)(P).w, d0, d1, d2, d3, i0, i1, i2, i3); }

    // ---- phase 1: clamped 3x3 box, flattened rows, 4-wide batched loads ----
    {
        int bx0 = max(ix - 1, 0), bx1 = min(ix + 1, GC - 1);
        int by0 = max(iy - 1, 0), by1 = min(iy + 1, GC - 1);
        int a0 = cst[by0 * GC + bx0];
        int l0 = cst[by0 * GC + bx1 + 1] - a0;
        int a1 = 0, l1 = 0, a2 = 0, l2 = 0;
        if (by0 + 1 <= by1) { a1 = cst[(by0 + 1) * GC + bx0]; l1 = cst[(by0 + 1) * GC + bx1 + 1] - a1; }
        if (by0 + 2 <= by1) { a2 = cst[(by0 + 2) * GC + bx0]; l2 = cst[(by0 + 2) * GC + bx1 + 1] - a2; }
        int l01 = l0 + l1;
        int m = l01 + l2;
        int f = s;
        for (; f + 24 < m; f += 32) {
            int f0 = f, f1 = f + 8, f2 = f + 16, f3 = f + 24;
            int j0 = f0 < l0 ? a0 + f0 : (f0 < l01 ? a1 + (f0 - l0) : a2 + (f0 - l01));
            int j1 = f1 < l0 ? a0 + f1 : (f1 < l01 ? a1 + (f1 - l0) : a2 + (f1 - l01));
            int j2 = f2 < l0 ? a0 + f2 : (f2 < l01 ? a1 + (f2 - l0) : a2 + (f2 - l01));
            int j3 = f3 < l0 ? a0 + f3 : (f3 < l01 ? a1 + (f3 - l0) : a2 + (f3 - l01));
            float4 p0 = gp[j0], p1 = gp[j1], p2 = gp[j2], p3 = gp[j3];
            INS1(p0); INS1(p1); INS1(p2); INS1(p3);
        }
        for (; f < m; f += 8) {
            int j = f < l0 ? a0 + f : (f < l01 ? a1 + (f - l0) : a2 + (f - l01));
            float4 p = gp[j];
            INS1(p);
        }
    }

#define MERGE_P(M) {                                                           \
        float e0 = __shfl_xor(d0, M), e1 = __shfl_xor(d1, M);                  \
        float e2 = __shfl_xor(d2, M), e3 = __shfl_xor(d3, M);                  \
        int j0 = __shfl_xor(i0, M), j1 = __shfl_xor(i1, M);                    \
        int j2 = __shfl_xor(i2, M), j3 = __shfl_xor(i3, M);                    \
        lexins(e0, j0, d0, d1, d2, d3, i0, i1, i2, i3);                        \
        lexins(e1, j1, d0, d1, d2, d3, i0, i1, i2, i3);                        \
        lexins(e2, j2, d0, d1, d2, d3, i0, i1, i2, i3);                        \
        lexins(e3, j3, d0, d1, d2, d3, i0, i1, i2, i3);                        \
    }
#define MERGE_D(M) {                                                           \
        float e0 = __shfl_xor(d0, M), e1 = __shfl_xor(d1, M);                  \
        float e2 = __shfl_xor(d2, M), e3 = __shfl_xor(d3, M);                  \
        int j0 = __shfl_xor(i0, M), j1 = __shfl_xor(i1, M);                    \
        int j2 = __shfl_xor(i2, M), j3 = __shfl_xor(i3, M);                    \
        lexins_d(e0, j0, d0, d1, d2, d3, i0, i1, i2, i3);                      \
        lexins_d(e1, j1, d0, d1, d2, d3, i0, i1, i2, i3);                      \
        lexins_d(e2, j2, d0, d1, d2, d3, i0, i1, i2, i3);                      \
        lexins_d(e3, j3, d0, d1, d2, d3, i0, i1, i2, i3);                      \
    }

    MERGE_P(1);
    MERGE_P(2);
    MERGE_P(4);

    auto done_at = [&](int r) -> bool {
        int bx0 = ix - r, bx1 = ix + r, by0 = iy - r, by1 = iy + r;
        float bound = 1e30f;
        if (bx0 > 0)      bound = fminf(bound, lx - (float)bx0 * CELLH);
        if (bx1 < GC - 1) bound = fminf(bound, (float)(bx1 + 1) * CELLH - lx);
        if (by0 > 0)      bound = fminf(bound, ly - (float)by0 * CELLH);
        if (by1 < GC - 1) bound = fminf(bound, (float)(by1 + 1) * CELLH - ly);
        bool covered = (bx0 <= 0 && bx1 >= GC - 1 && by0 <= 0 && by1 >= GC - 1);
        return covered || (d3 < bound * bound - 1e-5f);
    };

#define SCAN_RANGE_S(JLO, JHI)                                       \
    for (int j = (JLO) + s; j < (JHI); j += 8) {                     \
        float4 p = gp[j];                                            \
        INS1(p);                                                     \
    }

    int r = 1;
    bool need = !done_at(1);
    while (__any(need)) {
        ++r;
        if (need) {
            int ry0 = iy - r, ry1 = iy + r;
            int rx0 = ix - r, rx1 = ix + r;
            int ca = max(rx0, 0), cb = min(rx1, GC - 1);
            if (ry0 >= 0)      { int base = ry0 * GC; SCAN_RANGE_S(cst[base + ca], cst[base + cb + 1]); }
            if (ry1 <= GC - 1) { int base = ry1 * GC; SCAN_RANGE_S(cst[base + ca], cst[base + cb + 1]); }
            int ya = max(ry0 + 1, 0), yb = min(ry1 - 1, GC - 1);
            if (rx0 >= 0)      for (int cy = ya; cy <= yb; ++cy) { int c = cy * GC + rx0; SCAN_RANGE_S(cst[c], cst[c + 1]); }
            if (rx1 <= GC - 1) for (int cy = ya; cy <= yb; ++cy) { int c = cy * GC + rx1; SCAN_RANGE_S(cst[c], cst[c + 1]); }
            MERGE_D(1);
            MERGE_D(2);
            MERGE_D(4);
            need = !done_at(r);
        }
    }
#undef SCAN_RANGE_S
#undef MERGE_P
#undef MERGE_D
#undef INS1

    // ---- tail, split 8-way over channel chunks (t = s), bf16 gather ----
    int bb = bh >> 3, h = bh & 7;
    int qi = (g >> 2) & (NQ - 1);
    float power = fmaxf(sp[0], 0.0f) + 1e-6f;
    int idx[4] = {i0, i1, i2, i3};
    float z[4];
    #pragma unroll
    for (int u = 0; u < 4; ++u) {
        float kx = kvpos[(size_t)(bb * NKV + idx[u]) * 2 + 0];
        float ky = kvpos[(size_t)(bb * NKV + idx[u]) * 2 + 1];
        float dx = kx - lx;
        float dy = ky - ly;
        float dist = sqrtf(dx * dx + dy * dy) + 1e-6f;
        z[u] = -power * dist;
    }
    float m = fmaxf(fmaxf(z[0], z[1]), fmaxf(z[2], z[3]));
    float e0 = expf(z[0] - m), e1 = expf(z[1] - m), e2 = expf(z[2] - m), e3 = expf(z[3] - m);
    float esum = e0 + e1 + e2 + e3;
    float w0 = e0 / esum, w1 = e1 / esum, w2 = e2 / esum, w3 = e3 / esum;

    const ushort4* vp0 = (const ushort4*)(vwsb + ((size_t)bh * NKV + i0) * CH);
    const ushort4* vp1 = (const ushort4*)(vwsb + ((size_t)bh * NKV + i1) * CH);
    const ushort4* vp2 = (const ushort4*)(vwsb + ((size_t)bh * NKV + i2) * CH);
    const ushort4* vp3 = (const ushort4*)(vwsb + ((size_t)bh * NKV + i3) * CH);
    float a = attnw[g];
    float4* hp = (float4*)(head + ((size_t)(bb * NQ + qi)) * D + h * CH);
    {
        ushort4 u0 = vp0[s], u1 = vp1[s], u2 = vp2[s], u3 = vp3[s];
        float4 rr;
        rr.x = a * (w0 * bf2f(u0.x) + w1 * bf2f(u1.x) + w2 * bf2f(u2.x) + w3 * bf2f(u3.x));
        rr.y = a * (w0 * bf2f(u0.y) + w1 * bf2f(u1.y) + w2 * bf2f(u2.y) + w3 * bf2f(u3.y));
        rr.z = a * (w0 * bf2f(u0.z) + w1 * bf2f(u1.z) + w2 * bf2f(u2.z) + w3 * bf2f(u3.z));
        rr.w = a * (w0 * bf2f(u0.w) + w1 * bf2f(u1.w) + w2 * bf2f(u2.w) + w3 * bf2f(u3.w));
        rr.x += __shfl_xor(rr.x, 8); rr.x += __shfl_xor(rr.x, 16);  // sum over k
        rr.y += __shfl_xor(rr.y, 8); rr.y += __shfl_xor(rr.y, 16);
        rr.z += __shfl_xor(rr.z, 8); rr.z += __shfl_xor(rr.z, 16);
        rr.w += __shfl_xor(rr.w, 8); rr.w += __shfl_xor(rr.w, 16);
        if (((lane >> 3) & 3) == 0) hp[s] = rr;                     // k==0 lanes write
    }
}

// Fallback (ws too small): brute-force fused scan (round-4 validated path,
// bf16 value gather).  Requires loc/attnw/vwsb already computed by k_front.
__global__ void k_knn_fused(const float* __restrict__ kvpos, const float* __restrict__ loc,
                            const float* __restrict__ attnw, const ushortb* __restrict__ vwsb,
                            const float* __restrict__ sp, float* __restrict__ head) {
    #pragma clang fp contract(off)
    int g = blockIdx.x * 256 + threadIdx.x;
    int bh = g >> 12;
    int b = bh >> 3;
    __shared__ float sx[NKV];
    __shared__ float sy[NKV];
    __shared__ float sz[NKV];
    for (int n = threadIdx.x; n < NKV; n += 256) {
        float x = kvpos[(size_t)(b * NKV + n) * 2 + 0];
        float y = kvpos[(size_t)(b * NKV + n) * 2 + 1];
        sx[n] = -2.0f * x;
        sy[n] = -2.0f * y;
        sz[n] = x * x + y * y;
    }
    __syncthreads();
    float2 L = ((const float2*)loc)[g];
    float lx = L.x, ly = L.y;
    float sl = lx * lx + ly * ly;
    const float4* x4 = (const float4*)sx;
    const float4* y4 = (const float4*)sy;
    const float4* z4 = (const float4*)sz;
    float d0 = 1e30f, d1 = 1e30f, d2 = 1e30f, d3 = 1e30f;
    int i0 = 0, i1 = 0, i2 = 0, i3 = 0;
    for (int n = 0; n < NKV; n += 4) {
        int v = n >> 2;
        float4 xA = x4[v], yA = y4[v], zA = z4[v];
        float t0 = (sl + zA.x) + fmaf(ly, yA.x, lx * xA.x);
        float t1 = (sl + zA.y) + fmaf(ly, yA.y, lx * xA.y);
        float t2 = (sl + zA.z) + fmaf(ly, yA.z, lx * xA.z);
        float t3 = (sl + zA.w) + fmaf(ly, yA.w, lx * xA.w);
        bins4(t0, n + 0, d0, d1, d2, d3, i0, i1, i2, i3);
        bins4(t1, n + 1, d0, d1, d2, d3, i0, i1, i2, i3);
        bins4(t2, n + 2, d0, d1, d2, d3, i0, i1, i2, i3);
        bins4(t3, n + 3, d0, d1, d2, d3, i0, i1, i2, i3);
    }
    float power = fmaxf(sp[0], 0.0f) + 1e-6f;
    int h = bh & 7;
    int qi = (g >> 2) & (NQ - 1);
    int k = g & 3;
    int idx[4] = {i0, i1, i2, i3};
    float z[4];
    #pragma unroll
    for (int u = 0; u < 4; ++u) {
        float kx = kvpos[(size_t)(b * NKV + idx[u]) * 2 + 0];
        float ky = kvpos[(size_t)(b * NKV + idx[u]) * 2 + 1];
        float dx = kx - lx;
        float dy = ky - ly;
        float dist = sqrtf(dx * dx + dy * dy) + 1e-6f;
        z[u] = -power * dist;
    }
    float m = fmaxf(fmaxf(z[0], z[1]), fmaxf(z[2], z[3]));
    float e0 = expf(z[0] - m), e1 = expf(z[1] - m), e2 = expf(z[2] - m), e3 = expf(z[3] - m);
    float esum = e0 + e1 + e2 + e3;
    float w0 = e0 / esum, w1 = e1 / esum, w2 = e2 / esum, w3 = e3 / esum;
    const ushort4* vp0 = (const ushort4*)(vwsb + ((size_t)bh * NKV + i0) * CH);
    const ushort4* vp1 = (const ushort4*)(vwsb + ((size_t)bh * NKV + i1) * CH);
    const ushort4* vp2 = (const ushort4*)(vwsb + ((size_t)bh * NKV + i2) * CH);
    const ushort4* vp3 = (const ushort4*)(vwsb + ((size_t)bh * NKV + i3) * CH);
    float a = attnw[g];
    float4 acc[8];
    #pragma unroll
    for (int t = 0; t < 8; ++t) {
        ushort4 u0 = vp0[t], u1 = vp1[t], u2 = vp2[t], u3 = vp3[t];
        float4 r;
        r.x = a * (w0 * bf2f(u0.x) + w1 * bf2f(u1.x) + w2 * bf2f(u2.x) + w3 * bf2f(u3.x));
        r.y = a * (w0 * bf2f(u0.y) + w1 * bf2f(u1.y) + w2 * bf2f(u2.y) + w3 * bf2f(u3.y));
        r.z = a * (w0 * bf2f(u0.z) + w1 * bf2f(u1.z) + w2 * bf2f(u2.z) + w3 * bf2f(u3.z));
        r.w = a * (w0 * bf2f(u0.w) + w1 * bf2f(u1.w) + w2 * bf2f(u2.w) + w3 * bf2f(u3.w));
        r.x += __shfl_xor(r.x, 1); r.x += __shfl_xor(r.x, 2);
        r.y += __shfl_xor(r.y, 1); r.y += __shfl_xor(r.y, 2);
        r.z += __shfl_xor(r.z, 1); r.z += __shfl_xor(r.z, 2);
        r.w += __shfl_xor(r.w, 1); r.w += __shfl_xor(r.w, 2);
        acc[t] = r;
    }
    float4* hp = (float4*)(head + ((size_t)(b * NQ + qi)) * D + h * CH);
    hp[k * 2]     = acc[k * 2];
    hp[k * 2 + 1] = acc[k * 2 + 1];
}

// ---------------------------------------------------------------------------
// Kernel 4: out = head @ W_out + b_out  (f32 store; R9 version, 4 rows/block)
// ---------------------------------------------------------------------------
__global__ void k_out(const float* __restrict__ head, const float* __restrict__ Wout,
                      const float* __restrict__ bout, float* __restrict__ out) {
    int r0 = blockIdx.x * 4;
    __shared__ float hs[4][D];
    for (int t = threadIdx.x; t < 4 * D; t += 256) hs[t >> 8][t & 255] = head[(size_t)r0 * D + t];
    __syncthreads();
    int c = threadIdx.x;
    float a0 = 0.f, a1 = 0.f, a2 = 0.f, a3 = 0.f;
    for (int d = 0; d < D; ++d) {
        float w = Wout[d * D + c];
        a0 = fmaf(hs[0][d], w, a0); a1 = fmaf(hs[1][d], w, a1);
        a2 = fmaf(hs[2][d], w, a2); a3 = fmaf(hs[3][d], w, a3);
    }
    float bias = bout[c];
    out[(size_t)(r0 + 0) * D + c] = a0 + bias;
    out[(size_t)(r0 + 1) * D + c] = a1 + bias;
    out[(size_t)(r0 + 2) * D + c] = a2 + bias;
    out[(size_t)(r0 + 3) * D + c] = a3 + bias;
}

// ---------------------------------------------------------------------------
extern "C" void kernel_launch(void* const* d_in, const int* in_sizes, int n_in,
                              void* d_out, int out_size, void* d_ws, size_t ws_size,
                              hipStream_t stream) {
    (void)in_sizes; (void)n_in; (void)out_size;
    const float* q     = (const float*)d_in[0];
    const float* qpos  = (const float*)d_in[1];
    const float* kv    = (const float*)d_in[2];
    const float* kvp   = (const float*)d_in[3];
    const float* Woff  = (const float*)d_in[4];
    const float* boff  = (const float*)d_in[5];
    const float* Wattn = (const float*)d_in[6];
    const float* battn = (const float*)d_in[7];
    const float* Wv    = (const float*)d_in[8];
    const float* bv    = (const float*)d_in[9];
    const float* Wout  = (const float*)d_in[10];
    const float* bout  = (const float*)d_in[11];
    const float* sp    = (const float*)d_in[12];
    float* out = (float*)d_out;

    char* ws = (char*)d_ws;
    float* loc      = (float*)(ws + OFF_LOC);
    float* attnw    = (float*)(ws + OFF_ATTN);
    ushortb* vwsb   = (ushortb*)(ws + OFF_VWS);
    float* head     = (float*)(ws + OFF_HEAD);
    float4* pts4    = (float4*)(ws + OFF_PTS);
    int* cellStart  = (int*)(ws + OFF_CST);

    bool grid_ok = ws_size >= (size_t)WS_NEED;
    int nfront = (BATCH * NQ) / 2 + BATCH * NKV / 4 + (grid_ok ? BATCH : 0);
    hipLaunchKernelGGL(k_front, dim3(nfront), dim3(256), 0, stream,
                       q, qpos, Woff, boff, Wattn, battn, kv, Wv, bv, kvp,
                       loc, attnw, vwsb, pts4, cellStart);
    if (grid_ok) {
        hipLaunchKernelGGL(k_knn_grid2, dim3(BATCH * H * NQ * K / 32), dim3(256), 0, stream,
                           kvp, loc, attnw, vwsb, sp, pts4, cellStart, head);
    } else {
        hipLaunchKernelGGL(k_knn_fused, dim3(BATCH * H * NQ * K / 256), dim3(256), 0, stream,
                           kvp, loc, attnw, vwsb, sp, head);
    }
    hipLaunchKernelGGL(k_out, dim3(BATCH * NQ / 4), dim3(256), 0, stream,
                       head, Wout, bout, out);
}